// Round 8
// baseline (304.279 us; speedup 1.0000x reference)
//
#include <hip/hip_runtime.h>
#include <stdint.h>

#define TT 1024
#define AL 0.05f
#define OM 0.95f
#define STRD 408   // [c][.] row stride: 204 dwords, conflict-free for b128 c-major reads

typedef short s4v __attribute__((ext_vector_type(4)));
typedef short s8v __attribute__((ext_vector_type(8)));
typedef float f4v __attribute__((ext_vector_type(4)));
typedef float f16v __attribute__((ext_vector_type(16)));

#define MF32(a,b,c) __builtin_amdgcn_mfma_f32_32x32x16_bf16(a,b,c,0,0,0)
#define MF16(a,b,c) __builtin_amdgcn_mfma_f32_16x16x32_bf16(a,b,c,0,0,0)

__device__ __forceinline__ uint16_t f2bf(float f){ union{float f;uint32_t i;}t; t.f=f; return (uint16_t)((t.i + 0x7fffu + ((t.i>>16)&1u))>>16); }
__device__ __forceinline__ float bf2f(uint16_t h){ union{uint32_t i;float f;}t; t.i=((uint32_t)h)<<16; return t.f; }
__device__ __forceinline__ uint32_t pk2bf(float a, float b){
#if __has_builtin(__builtin_amdgcn_cvt_pk_bf16_f32)
  typedef __bf16 bf2v __attribute__((ext_vector_type(2)));
  bf2v r = __builtin_amdgcn_cvt_pk_bf16_f32(a, b);
  uint32_t u; __builtin_memcpy(&u, &r, 4); return u;
#else
  return (uint32_t)f2bf(a) | ((uint32_t)f2bf(b) << 16);
#endif
}
__device__ __forceinline__ s8v ld8(const uint16_t* p){ return *(const s8v*)p; }
#define ROWF(e2) (((e2)&3) + 8*((e2)>>2) + 4*h2)
// XOR bank swizzle for 64B-row [v][32] arrays: odd rows swap 32B halves -> full 32-bank coverage
#define SW(rw, of) ((of) ^ (((rw)&1)<<4))

// staging buffer for output transpose
__device__ __align__(16) float gStage[32*12*12800];

// S map (u16), total 81568 = 163.1 KB:
//  X1S    0..12800   x1 [v][32] swz         ; MLP: H1 feat (raw)
//  X2S 12800..25600  x2 [v][32] swz         ; MLP: G1 feat (raw)
//  XCV 25600..38656  X->Xr [c][408]         ; step2: P1 (swz [w][32]) ; MLP: H2' feat swz
//  PBA 38656..54656  phaseL XT+W ; P0 both steps (swz, 12800) ; +12800: RS/CS bf16 ; MLP: G2' feat swz
//  HCV 54656..67712  stats rs/cs fp32 ; step1: P1 ; H1*rinv [c][408] ; MLP: folded weights+bias
//  GCV 67712..80768  Xc [c][408] ; step2: G1*cinv [c][408]
//  RINV 80768..81168, CINV 81168..81568 (bf16)
#define X1S 0
#define X2S 12800
#define XCV 25600
#define PBA 38656
#define HCV 54656
#define GCV 67712
#define RINV 80768
#define CINV 81168
#define RSA (PBA + 12800)
#define CSA (PBA + 13200)

__global__ __launch_bounds__(TT) void dymix(
    const float* __restrict__ x,
    const float* __restrict__ w1, const float* __restrict__ b1,
    const float* __restrict__ w2, const float* __restrict__ b2,
    const float* __restrict__ wm1, const float* __restrict__ bm1,
    const float* __restrict__ wm2, const float* __restrict__ bm2)
{
  __shared__ __align__(16) uint16_t S[81568];

  const int blk = blockIdx.x;
  const int xcd = blk & 7, slot = blk >> 3;
  const int n = xcd*4 + slot/12;
  const int l = slot - (slot/12)*12;
  const int t = threadIdx.x;
  const int wv = t >> 6;        // 0..15
  const int lane = t & 63;
  const int q  = lane >> 4;
  const int r  = lane & 15;
  const int h2 = lane >> 5;
  const int m32 = lane & 31;
  const long xbase = (long)n*153600 + l;

  // ---------- Phase 0: stage X -> XCV [c][408] ----------
  for (int i = t; i < 12800; i += TT) {
    int c = i / 400, v = i - c*400;
    S[XCV + c*STRD + v] = f2bf(x[xbase + (long)i*12]);
  }
  __syncthreads();

  // ---------- Phase L prep: XT (unswizzled) + lin weights into PBA ----------
  for (int i = t; i < 12800; i += TT) { int v = i>>5, c = i&31; S[PBA + i] = S[XCV + c*STRD + v]; }
  for (int i = t; i < 1024; i += TT) {
    int o = i>>5, c = i&31;
    S[PBA + 12800 + o*40 + c] = f2bf(w1[i]);
    S[PBA + 14080 + o*40 + c] = f2bf(w2[i]);
  }
  if (t < 32) { ((float*)(S+PBA+15360))[t] = b1[t]; ((float*)(S+PBA+15424))[t] = b2[t]; }
  __syncthreads();

  // ---------- Phase L: x1 = tanh(W1 X + b1), x2 = tanh(W2 X + b2) -> [v][32] swizzled ----------
  #pragma unroll
  for (int j = 0; j < 2; ++j) {
    int u = wv + 16*j;
    if (u < 24) {
      int nt = u >> 1, li = u & 1;
      const uint16_t* W = S + PBA + 12800 + li*1280;
      const float* bf = (const float*)(S + PBA + 15360 + li*64);
      uint16_t* dst = S + (li ? X2S : X1S);
      f16v z = {};
      #pragma unroll
      for (int kk = 0; kk < 2; ++kk) {
        s8v a = ld8(W + m32*40 + kk*16 + h2*8);
        s8v b = ld8(S + PBA + (nt*32 + m32)*32 + kk*16 + h2*8);
        z = MF32(a, b, z);
      }
      int v = nt*32 + m32;
      #pragma unroll
      for (int gg = 0; gg < 4; ++gg) {
        uint2 d;
        float e0 = tanhf(z[4*gg+0] + bf[8*gg + 4*h2 + 0]);
        float e1 = tanhf(z[4*gg+1] + bf[8*gg + 4*h2 + 1]);
        float e2 = tanhf(z[4*gg+2] + bf[8*gg + 4*h2 + 2]);
        float e3 = tanhf(z[4*gg+3] + bf[8*gg + 4*h2 + 3]);
        d.x = pk2bf(e0, e1); d.y = pk2bf(e2, e3);
        *(uint2*)(dst + v*32 + SW(v, 8*gg + 4*h2)) = d;
      }
    } else if (u < 28) {
      int li = (u-24)>>1, mt = u&1;
      const uint16_t* W = S + PBA + 12800 + li*1280;
      const float* bf = (const float*)(S + PBA + 15360 + li*64);
      uint16_t* dst = S + (li ? X2S : X1S);
      s8v a = ld8(W + (mt*16 + r)*40 + q*8);
      s8v b = ld8(S + PBA + (384 + r)*32 + q*8);
      f4v z4 = {}; z4 = MF16(a, b, z4);
      uint2 d;
      d.x = pk2bf(tanhf(z4[0] + bf[mt*16 + q*4 + 0]), tanhf(z4[1] + bf[mt*16 + q*4 + 1]));
      d.y = pk2bf(tanhf(z4[2] + bf[mt*16 + q*4 + 2]), tanhf(z4[3] + bf[mt*16 + q*4 + 3]));
      *(uint2*)(dst + (384 + r)*32 + SW(384 + r, mt*16 + q*4)) = d;
    }
  }
  // preload MLP X b-frags from XT (raw X; XT dies when diffusion starts)
  s8v xf0, xf1, xft;
  {
    int m0 = (wv < 12) ? wv : 0;
    xf0 = ld8(S + PBA + (m0*32 + m32)*32 + h2*8);
    xf1 = ld8(S + PBA + (m0*32 + m32)*32 + 16 + h2*8);
    xft = ld8(S + PBA + (384 + r)*32 + q*8);
  }
  __syncthreads();

  // ---------- Stats: rowsum/colsum of exp(A) ----------
  float* rsf = (float*)(S + HCV);
  float* csf = rsf + 400;
  for (int i = t; i < 400; i += TT) csf[i] = 0.f;
  __syncthreads();
  {
    s8v av[2]; f4v rac[2] = {{},{}};
    #pragma unroll
    for (int jj = 0; jj < 2; ++jj) {
      int vt = wv + 16*jj;
      if (vt < 25) av[jj] = ld8(S + X1S + (vt*16 + r)*32 + SW(vt*16 + r, q*8));
    }
    for (int wt = 0; wt < 25; ++wt) {
      s8v b = ld8(S + X2S + (wt*16 + r)*32 + SW(wt*16 + r, q*8));
      float cp = 0.f;
      #pragma unroll
      for (int jj = 0; jj < 2; ++jj) {
        int vt = wv + 16*jj;
        if (vt < 25) {
          f4v z = {}; z = MF16(av[jj], b, z);
          #pragma unroll
          for (int e = 0; e < 4; ++e) { float ev = __expf(z[e]); rac[jj][e] += ev; cp += ev; }
        }
      }
      cp += __shfl_xor(cp, 16); cp += __shfl_xor(cp, 32);
      if (q == 0) atomicAdd(&csf[wt*16 + r], cp);
    }
    #pragma unroll
    for (int jj = 0; jj < 2; ++jj) {
      int vt = wv + 16*jj;
      if (vt < 25) {
        #pragma unroll
        for (int e = 0; e < 4; ++e) {
          float s = rac[jj][e];
          s += __shfl_xor(s,1); s += __shfl_xor(s,2); s += __shfl_xor(s,4); s += __shfl_xor(s,8);
          if (r == 0) rsf[vt*16 + q*4 + e] = s;
        }
      }
    }
  }
  __syncthreads();
  // scale fold: RINV/CINV/RS/CS bf16; Xr=X*rinv (XCV in-place), Xc=X*cinv -> GCV
  for (int i = t; i < 400; i += TT) {
    S[RINV + i] = f2bf(1.f/rsf[i]);
    S[CINV + i] = f2bf(1.f/csf[i]);
    S[RSA  + i] = f2bf(rsf[i]);
    S[CSA  + i] = f2bf(csf[i]);
  }
  for (int i = t; i < 12800; i += TT) {
    int c = i / 400, v = i - c*400;
    float ri = 1.f/rsf[v], ci = 1.f/csf[v];
    float xv = bf2f(S[XCV + c*STRD + v]);
    S[XCV + c*STRD + v] = f2bf(xv * ri);
    S[GCV + c*STRD + v] = f2bf(xv * ci);
  }
  __syncthreads();

  // ---------- hoist slab-invariant T b-frags (w-tile rows; fixed across slabs & steps) ----------
  s8v tb0[2], tb1[2], tbt;
  #pragma unroll
  for (int jj = 0; jj < 2; ++jj) {
    int g = wv + 16*jj;
    if (g >= 26) continue;
    int chain = (g < 13) ? 0 : 1;
    int uu = g - 13*chain;
    const uint16_t* sb2 = S + (chain ? X1S : X2S);
    if (uu < 12) {
      int row = uu*32 + m32;
      tb0[jj] = ld8(sb2 + row*32 + SW(row, h2*8));
      tb1[jj] = ld8(sb2 + row*32 + SW(row, 16 + h2*8));
    } else {
      tbt = ld8(sb2 + (384 + r)*32 + SW(384 + r, q*8));
    }
  }

  // ---------- Diffusion: wave-private producer/consumer, P = raw exp(A), scales folded into A-operands ----------
  f16v acc[2];
  for (int step = 0; step < 2; ++step) {
    { f16v zv = {}; acc[0]=zv; acc[1]=zv; }
    const uint16_t* AH = S + (step ? HCV : XCV);   // Xr then H1*rinv
    const uint16_t* AG = S + GCV;                  // Xc then G1*cinv
    uint16_t* P0 = S + PBA;
    uint16_t* P1 = S + (step ? XCV : HCV);
    for (int sb = 0; sb < 13; ++sb) {
      const int vbase = sb*32;
      const bool lastsb = (sb == 12);
      // ---- T: produce this wave's P rows (raw exp) ----
      #pragma unroll
      for (int jj = 0; jj < 2; ++jj) {
        int g = wv + 16*jj;
        if (g >= 26) continue;
        int chain = (g < 13) ? 0 : 1;
        int uu = g - 13*chain;
        uint16_t* P = chain ? P1 : P0;
        const uint16_t* sa = S + (chain ? X2S : X1S);
        if (uu < 12) {
          int row0 = vbase + m32;
          s8v a0 = ld8(sa + row0*32 + SW(row0, h2*8));
          s8v a1 = ld8(sa + row0*32 + SW(row0, 16 + h2*8));
          f16v z = {}; z = MF32(a0, tb0[jj], z); z = MF32(a1, tb1[jj], z);
          uint16_t* pw = P + (uu*32 + m32)*32;
          int gmax = lastsb ? 2 : 4;
          for (int gg = 0; gg < gmax; ++gg) {
            uint2 d;
            d.x = pk2bf(__expf(z[4*gg+0]), __expf(z[4*gg+1]));
            d.y = pk2bf(__expf(z[4*gg+2]), __expf(z[4*gg+3]));
            *(uint2*)(pw + SW(uu*32 + m32, 8*gg + 4*h2)) = d;
          }
        } else {
          int ctmax = lastsb ? 1 : 2;
          for (int ct = 0; ct < ctmax; ++ct) {
            int rowa = vbase + ct*16 + r;
            s8v a = ld8(sa + rowa*32 + SW(rowa, q*8));
            f4v z4 = {}; z4 = MF16(a, tbt, z4);
            uint2 d;
            d.x = pk2bf(__expf(z4[0]), __expf(z4[1]));
            d.y = pk2bf(__expf(z4[2]), __expf(z4[3]));
            *(uint2*)(P + (384 + r)*32 + SW(384 + r, ct*16 + q*4)) = d;
          }
          if (lastsb && lane < 16) {
            uint2 z0 = {0u,0u};
            int rowz = 384 + lane;
            #pragma unroll
            for (int j4 = 0; j4 < 4; ++j4)
              *(uint2*)(P + rowz*32 + SW(rowz, 16 + 4*j4)) = z0;
          }
        }
      }
      // ---- GEMM: consume this wave's own P rows (in-wave lgkm ordering, no barrier) ----
      #pragma unroll
      for (int jj = 0; jj < 2; ++jj) {
        int g = wv + 16*jj;
        if (g >= 26) continue;
        int chain = (g < 13) ? 0 : 1;
        int uu = g - 13*chain;
        uint16_t* P = chain ? P1 : P0;
        const uint16_t* Acv = chain ? AG : AH;
        if (uu < 12) {
          int kmax = lastsb ? 1 : 2;
          for (int kk = 0; kk < kmax; ++kk) {
            s8v a = ld8(Acv + m32*STRD + vbase + kk*16 + h2*8);
            s8v b = ld8(P + (uu*32 + m32)*32 + SW(uu*32 + m32, kk*16 + h2*8));
            acc[jj] = MF32(a, b, acc[jj]);
          }
        } else {
          #pragma unroll
          for (int mt2 = 0; mt2 < 2; ++mt2) {
            int koff = (lastsb && q >= 2) ? 0 : q*8;   // pad cols never written — NaN guard (×0 in P)
            s8v a = ld8(Acv + (mt2*16 + r)*STRD + vbase + koff);
            s8v b = ld8(P + (384 + r)*32 + SW(384 + r, q*8));
            f4v c4 = { acc[jj][4*mt2+0], acc[jj][4*mt2+1], acc[jj][4*mt2+2], acc[jj][4*mt2+3] };
            c4 = MF16(a, b, c4);
            acc[jj][4*mt2+0]=c4[0]; acc[jj][4*mt2+1]=c4[1]; acc[jj][4*mt2+2]=c4[2]; acc[jj][4*mt2+3]=c4[3];
          }
        }
      }
    } // sb
    __syncthreads();
    if (step == 0) {
      // epilogue: X = Xr*rs ; H1 = AL*X + OM*acc, store H1*rinv -> HCV ; G1*cinv -> GCV
      #pragma unroll
      for (int jj = 0; jj < 2; ++jj) {
        int g = wv + 16*jj;
        if (g >= 26) continue;
        int chain = (g < 13) ? 0 : 1;
        int uu = g - 13*chain;
        uint16_t* dst = S + (chain ? GCV : HCV);
        if (uu < 12) {
          int w = uu*32 + m32;
          float rsw = bf2f(S[RSA + w]);
          float sc  = bf2f(S[(chain ? CINV : RINV) + w]);
          #pragma unroll
          for (int e2 = 0; e2 < 16; ++e2) {
            int c = ROWF(e2);
            float xv = bf2f(S[XCV + c*STRD + w]) * rsw;
            dst[c*STRD + w] = f2bf((AL*xv + OM*acc[jj][e2]) * sc);
          }
        } else {
          int w = 384 + r;
          float rsw = bf2f(S[RSA + w]);
          float sc  = bf2f(S[(chain ? CINV : RINV) + w]);
          #pragma unroll
          for (int mt2 = 0; mt2 < 2; ++mt2)
            #pragma unroll
            for (int e = 0; e < 4; ++e) {
              int c = mt2*16 + q*4 + e;
              float xv = bf2f(S[XCV + c*STRD + w]) * rsw;
              dst[c*STRD + w] = f2bf((AL*xv + OM*acc[jj][4*mt2+e]) * sc);
            }
        }
      }
      __syncthreads();
    }
  } // step

  // ---------- MLP prep: raw features to [v][32] swz; weights folded into HCV ----------
  for (int i = t; i < 12800; i += TT) {
    int v = i >> 5, c = i & 31;
    S[X1S + v*32 + SW(v, c)] = f2bf(bf2f(S[HCV + c*STRD + v]) * bf2f(S[RSA + v]));  // H1 raw
    S[X2S + v*32 + SW(v, c)] = f2bf(bf2f(S[GCV + c*STRD + v]) * bf2f(S[CSA + v]));  // G1 raw
  }
  #pragma unroll
  for (int jj = 0; jj < 2; ++jj) {
    int g = wv + 16*jj;
    if (g >= 26) continue;
    int chain = (g < 13) ? 0 : 1;
    int uu = g - 13*chain;
    uint16_t* dst = S + (chain ? PBA : XCV);   // H2' -> XCV, G2' -> PBA (swz [v][32])
    if (uu < 12) {
      int w = uu*32 + m32;
      #pragma unroll
      for (int gg = 0; gg < 4; ++gg) {
        uint2 d;
        d.x = pk2bf(OM*acc[jj][4*gg+0], OM*acc[jj][4*gg+1]);
        d.y = pk2bf(OM*acc[jj][4*gg+2], OM*acc[jj][4*gg+3]);
        *(uint2*)(dst + w*32 + SW(w, 8*gg + 4*h2)) = d;
      }
    } else {
      int w = 384 + r;
      #pragma unroll
      for (int mt2 = 0; mt2 < 2; ++mt2) {
        uint2 d;
        d.x = pk2bf(OM*acc[jj][4*mt2+0], OM*acc[jj][4*mt2+1]);
        d.y = pk2bf(OM*acc[jj][4*mt2+2], OM*acc[jj][4*mt2+3]);
        *(uint2*)(dst + w*32 + SW(w, mt2*16 + q*4)) = d;
      }
    }
  }
  __syncthreads();
  for (int i = t; i < 1024; i += TT) {
    int o = i >> 5, c = i & 31;
    float h2w = wm1[o*96 + 64 + c], g2w = wm2[o*96 + 64 + c];
    S[HCV +        o*40 + c] = f2bf(wm1[o*96 + c] + wm2[o*96 + c] + AL*(h2w + g2w));
    S[HCV + 1280 + o*40 + c] = f2bf(wm1[o*96 + 32 + c]);
    S[HCV + 2560 + o*40 + c] = f2bf(h2w);
    S[HCV + 3840 + o*40 + c] = f2bf(wm2[o*96 + 32 + c]);
    S[HCV + 5120 + o*40 + c] = f2bf(g2w);
  }
  if (t < 32) ((float*)(S + HCV + 6400))[t] = bm1[t] + bm2[t];
  __syncthreads();

  // ---------- MLP + coalesced staged store to gStage[n][l][o][v] ----------
  {
    const float* boF = (const float*)(S + HCV + 6400);
    float* oSl = gStage + (long)(n*12 + l)*12800;
    const int fb[5] = { 0, X1S, XCV, X2S, PBA };   // X(regs), H1, H2', G1, G2'
    int m = wv;
    if (m < 12) {
      f16v z = {};
      #pragma unroll
      for (int p = 0; p < 5; ++p) {
        #pragma unroll
        for (int kk = 0; kk < 2; ++kk) {
          s8v a = ld8(S + HCV + p*1280 + m32*40 + kk*16 + h2*8);
          s8v b;
          if (p == 0) b = kk ? xf1 : xf0;
          else        b = ld8(S + fb[p] + (m*32 + m32)*32 + SW(m*32 + m32, kk*16 + h2*8));
          z = MF32(a, b, z);
        }
      }
      int v = m*32 + m32;
      #pragma unroll
      for (int e2 = 0; e2 < 16; ++e2) {
        int o = ROWF(e2);
        oSl[o*400 + v] = z[e2] + boF[o];
      }
    } else if (m < 14) {
      int mt = m - 12;
      f4v z4 = {};
      #pragma unroll
      for (int p = 0; p < 5; ++p) {
        s8v a = ld8(S + HCV + p*1280 + (mt*16 + r)*40 + q*8);
        s8v b = (p == 0) ? xft : ld8(S + fb[p] + (384 + r)*32 + SW(384 + r, q*8));
        z4 = MF16(a, b, z4);
      }
      #pragma unroll
      for (int e = 0; e < 4; ++e) {
        int o = mt*16 + q*4 + e;
        oSl[o*400 + 384 + r] = z4[e] + boF[o];
      }
    }
  }
}

// Plain transpose kernel: gStage[n][l][o][v] -> out[n][o][v][l] (both sides coalesced)
__global__ __launch_bounds__(256) void finT(float* __restrict__ out) {
  int idx = blockIdx.x*256 + threadIdx.x;      // n*12800 + ov
  int n = idx / 12800, ov = idx - n*12800;
  const float* src = gStage + (long)n*153600 + ov;
  float vals[12];
  #pragma unroll
  for (int l = 0; l < 12; ++l) vals[l] = src[(long)l*12800];
  float4* dst = (float4*)(out + (long)idx*12);
  dst[0] = make_float4(vals[0],vals[1],vals[2],vals[3]);
  dst[1] = make_float4(vals[4],vals[5],vals[6],vals[7]);
  dst[2] = make_float4(vals[8],vals[9],vals[10],vals[11]);
}

extern "C" void kernel_launch(void* const* d_in, const int* in_sizes, int n_in,
                              void* d_out, int out_size, void* d_ws, size_t ws_size,
                              hipStream_t stream) {
  (void)in_sizes; (void)n_in; (void)out_size; (void)d_ws; (void)ws_size;
  dymix<<<dim3(384), dim3(TT), 0, stream>>>(
      (const float*)d_in[0],
      (const float*)d_in[1], (const float*)d_in[2],
      (const float*)d_in[3], (const float*)d_in[4],
      (const float*)d_in[5], (const float*)d_in[6],
      (const float*)d_in[7], (const float*)d_in[8]);
  finT<<<dim3(1600), dim3(256), 0, stream>>>((float*)d_out);
}